// Round 5
// baseline (9686.231 us; speedup 1.0000x reference)
//
#include <hip/hip_runtime.h>

// Problem constants
#define NPOS   158   // 64 query + 94 doc token positions per batch
#define EPITCH 136   // shorts per staged emb row (128 + 8 pad)

// workspace layout (bytes)
#define RKP_SHORTS (2*8*8*8*64*8)          // 524288: [dir][r8][ks8][f8][lane64][j8]
#define KP_SHORTS  (2*64*4*512)            // k packed for xzgemm
#define XZ_HALFS   ((size_t)2*128*158*1024)
#define OFF_KP     ((size_t)RKP_SHORTS*2)                 // 1,048,576
#define OFF_XZ     (OFF_KP + (size_t)KP_SHORTS*2)         // 1,572,864
#define OFF_HB     (OFF_XZ + XZ_HALFS*2)                  // 84,410,368  (32 groups x 256 KB)
#define OFF_CTR    (OFF_HB + (size_t)32*262144)           // 92,798,976  (32 ints)

typedef __attribute__((ext_vector_type(8))) short    short8;
typedef __attribute__((ext_vector_type(4))) short    short4v;
typedef __attribute__((ext_vector_type(4))) float    float4v;
typedef __attribute__((ext_vector_type(8))) _Float16 half8;

__device__ __forceinline__ unsigned short f2bf(float x){
  unsigned int u = __builtin_bit_cast(unsigned int, x);
  u += 0x7FFFu + ((u >> 16) & 1u);           // round-to-nearest-even
  return (unsigned short)(u >> 16);
}
__device__ __forceinline__ float fsig(float x){
  return 1.0f/(1.0f + __expf(-x));
}
__device__ __forceinline__ float ftanh(float x){
  float ax = fabsf(x);
  float e  = __expf(-2.0f*ax);
  float r  = (1.0f - e)/(1.0f + e);
  return (x < 0.0f) ? -r : r;
}

// ---------------------------------------------------------------------------
// Pack rk per (dir, role r) into the B-fragment order the LDS-resident slice
// uses: rkp[d][r][ks][f][lane][j], f = gate*2+tj, nt = gate*16 + r*2 + tj,
// element = rk[k = ks*32+(lane>>4)*8+j][col = nt*16+(lane&15)].
// Also pack k (for xzgemm): kp[dir][nt64][ks4][lane64][j8].
// ---------------------------------------------------------------------------
__global__ void prepack(const float* __restrict__ kf, const float* __restrict__ rkf,
                        const float* __restrict__ kb, const float* __restrict__ rkb,
                        unsigned short* __restrict__ rkp, unsigned short* __restrict__ kp){
  int idx = blockIdx.x*256 + threadIdx.x;
  if (idx < RKP_SHORTS){
    int j = idx & 7, lane = (idx>>3)&63, f = (idx>>9)&7, ks = (idx>>12)&7,
        rr = (idx>>15)&7, d = (idx>>18)&1;
    int gate = f>>1, tj = f&1;
    int nt  = gate*16 + rr*2 + tj;
    int k   = ks*32 + (lane>>4)*8 + j;
    int col = nt*16 + (lane&15);
    const float* RK = d ? rkb : rkf;
    rkp[idx] = f2bf(RK[k*1024 + col]);
  } else {
    int i2 = idx - RKP_SHORTS;
    if (i2 < KP_SHORTS){
      int j = i2 & 7, lane = (i2>>3)&63, ks = (i2>>9)&3, nt = (i2>>11)&63, d = i2>>17;
      const float* K = d ? kb : kf;
      int k   = ks*32 + (lane>>4)*8 + j;
      int col = nt*16 + (lane&15);
      kp[i2] = f2bf(K[k*1024 + col]);
    }
  }
}

// ---------------------------------------------------------------------------
// xz[dir][bat][pos][1024] (fp16) = emb @ k + bias, inner layout
// [pos][r 8][lc 16][n 8], n = gate*2+tj  (r = consumer block's role).
// ---------------------------------------------------------------------------
__launch_bounds__(512)
__global__ void xzgemm(const int* __restrict__ inputs, const float* __restrict__ emb,
                       const unsigned short* __restrict__ kpack,
                       const float* __restrict__ b_f, const float* __restrict__ b_b,
                       _Float16* __restrict__ xz){
  __shared__ int tokp[32];
  __shared__ __align__(16) short e_lds[32*EPITCH];
  const int bid = blockIdx.x;
  const int pt  = bid % 5;
  const int bd  = bid / 5;
  const int bat = bd & 127, dir = bd >> 7;
  const int tid = threadIdx.x, lane = tid & 63, wv = tid >> 6;
  const int lc  = lane & 15, q = lane >> 4;

  for (int i = tid; i < 32*EPITCH; i += 512) e_lds[i] = 0;
  if (tid < 32){
    int p = pt*32 + tid;
    tokp[tid] = (p < NPOS) ? inputs[bat*NPOS + p] : 0;
  }
  __syncthreads();
  for (int idx = tid; idx < 32*32; idx += 512){
    int i = idx >> 5, c4 = (idx & 31) << 2;
    int p = pt*32 + i;
    if (p < NPOS){
      float4v v = *(const float4v*)(emb + (long)tokp[i]*128 + c4);
      short4v s;
      s[0]=(short)f2bf(v[0]); s[1]=(short)f2bf(v[1]);
      s[2]=(short)f2bf(v[2]); s[3]=(short)f2bf(v[3]);
      *(short4v*)&e_lds[i*EPITCH + c4] = s;
    }
  }
  __syncthreads();

  const float* bias = dir ? b_b : b_f;
  float4v acc[2][8];
  #pragma unroll
  for (int g = 0; g < 4; ++g)
    #pragma unroll
    for (int tj = 0; tj < 2; ++tj){
      float bv = bias[g*256 + wv*32 + tj*16 + lc];
      acc[0][g*2+tj] = (float4v){bv,bv,bv,bv};
      acc[1][g*2+tj] = acc[0][g*2+tj];
    }

  const short8* KP = (const short8*)kpack + (long)dir*64*4*64;
  #pragma unroll
  for (int ks = 0; ks < 4; ++ks){
    short8 a0 = *(const short8*)&e_lds[lc*EPITCH + ks*32 + q*8];
    short8 a1 = *(const short8*)&e_lds[(16+lc)*EPITCH + ks*32 + q*8];
    #pragma unroll
    for (int n = 0; n < 8; ++n){
      int g = n >> 1, tj = n & 1;
      int nt = g*16 + wv*2 + tj;
      short8 b = KP[(nt*4 + ks)*64 + lane];
      acc[0][n] = __builtin_amdgcn_mfma_f32_16x16x32_bf16(a0, b, acc[0][n], 0, 0, 0);
      acc[1][n] = __builtin_amdgcn_mfma_f32_16x16x32_bf16(a1, b, acc[1][n], 0, 0, 0);
    }
  }

  _Float16* xzb = xz + ((long)(dir*128 + bat))*NPOS*1024;
  #pragma unroll
  for (int mt = 0; mt < 2; ++mt)
    #pragma unroll
    for (int r = 0; r < 4; ++r){
      int row = mt*16 + q*4 + r;
      int p = pt*32 + row;
      if (p < NPOS){
        half8 hv;
        #pragma unroll
        for (int n = 0; n < 8; ++n) hv[n] = (_Float16)acc[mt][n][r];
        __builtin_nontemporal_store(hv, (half8*)(xzb + (long)p*1024 + wv*128 + lc*8));
      }
    }
}

// ---------------------------------------------------------------------------
// Systolic recurrent kernel. 32 groups x 8 blocks. Group g: dir = g>>4,
// batches (g&15)*8..+8 (256 chains, M=256). Block role r keeps its 128-col
// rk slice permanently in LDS (64 KB) -> ZERO weight re-streaming. Per step:
// z[256x128] via MFMA (A = h fragments from group's global h-buffer, double
// buffered), gates for j in [r*32, r*32+32), write h-slice, device-scope
// group barrier (counter + release/acquire fences; correct cross-XCD).
// Wave wv owns batch (g&15)*8+wv: its 32 chains x block's 128 cols.
// ---------------------------------------------------------------------------
__launch_bounds__(512)
__global__ void lstm_rec(const int* __restrict__ inputs, const _Float16* __restrict__ xz,
                         const unsigned short* __restrict__ rkpack,
                         const float* __restrict__ wci_f, const float* __restrict__ wcf_f,
                         const float* __restrict__ wco_f,
                         const float* __restrict__ wci_b, const float* __restrict__ wcf_b,
                         const float* __restrict__ wco_b,
                         char* __restrict__ ws)
{
  __shared__ __align__(16) short wk[8*8*512];   // exactly 64 KB: [(ks*8+f)*512 + lane*8 + j]

  const int tid  = threadIdx.x;
  const int lane = tid & 63;
  const int wv   = tid >> 6;
  const int lc   = lane & 15;
  const int q    = lane >> 4;

  // block -> (group, role); same-XCD grouping heuristic under blockIdx%8 RR
  const int gb = blockIdx.x;
  const int x  = gb & 7, v = gb >> 3;
  const int gq = v >> 3, r = v & 7;          // r = j-slice role 0..7
  const int g  = gq*8 + x;                    // group 0..31
  const int dir = g >> 4;
  const int bs  = g & 15;
  const int bat = bs*8 + wv;                  // this wave's batch

  char* HBg = ws + OFF_HB + (size_t)g*262144;
  int*  ctr = (int*)(ws + OFF_CTR) + g;

  // ---- stage rk slice into LDS (read once, resident all 64 steps) ----
  const short8* RS = (const short8*)rkpack + (size_t)(dir*8 + r)*4096;
  short8* WK = (short8*)wk;
  for (int i = tid; i < 4096; i += 512) WK[i] = RS[i];

  // ---- per-wave masks via ballot (no LDS) ----
  unsigned long long m0 = __ballot(inputs[bat*NPOS + lane] != 0);
  unsigned long long m1 = __ballot(inputs[bat*NPOS + 64 + lane] != 0);
  int p2 = 128 + lane;
  unsigned long long m2 = __ballot((p2 < NPOS) && (inputs[bat*NPOS + p2] != 0));

  // ---- zero h buffer 0 (this block's ks=r slice, all 16 m-tiles) ----
  {
    short8 z = (short8){0,0,0,0,0,0,0,0};
    short8* B0 = (short8*)HBg;
    for (int i = tid; i < 1024; i += 512){
      int mt = i >> 6, ln = i & 63;
      B0[(mt*8 + r)*64 + ln] = z;
    }
  }

  // peephole constants
  const float* wci = dir ? wci_b : wci_f;
  const float* wcf = dir ? wcf_b : wcf_f;
  const float* wco = dir ? wco_b : wco_f;
  float wcir[2], wcfr[2], wcor[2];
  #pragma unroll
  for (int tj = 0; tj < 2; ++tj){
    int j = r*32 + tj*16 + lc;
    wcir[tj] = wci[j]; wcfr[tj] = wcf[j]; wcor[tj] = wco[j];
  }

  float hreg[2][4][2], creg[2][4][2];
  #pragma unroll
  for (int mt = 0; mt < 2; ++mt)
    #pragma unroll
    for (int rr = 0; rr < 4; ++rr)
      #pragma unroll
      for (int tj = 0; tj < 2; ++tj){ hreg[mt][rr][tj] = 0.f; creg[mt][rr][tj] = 0.f; }

  const _Float16* xzb = xz + ((long)(dir*128 + bat))*NPOS*1024 + r*128 + lc*8;

  // ---- group barrier: release fence + counter add + bounded spin + acquire ----
  #define GBAR(TGT)                                                              \
  {                                                                              \
    __threadfence();                                                             \
    __syncthreads();                                                             \
    if (tid == 0){                                                               \
      __hip_atomic_fetch_add(ctr, 1, __ATOMIC_RELEASE, __HIP_MEMORY_SCOPE_AGENT);\
      int it_ = 0;                                                               \
      while (__hip_atomic_load(ctr, __ATOMIC_RELAXED, __HIP_MEMORY_SCOPE_AGENT)  \
             < (TGT) && it_ < (1<<23)){ __builtin_amdgcn_s_sleep(2); ++it_; }    \
    }                                                                            \
    __syncthreads();                                                             \
    __threadfence();                                                             \
  }

  GBAR(8);   // h zeros + weight staging visible group-wide

  for (int s = 0; s < 64; ++s){
    const int t = dir ? (63 - s) : s;
    const short8* Rb = (const short8*)(HBg + (size_t)(s & 1)*131072);
    unsigned short* Wb = (unsigned short*)(HBg + (size_t)((s & 1) ^ 1)*131072);

    // prefetch this step's xz (consumed in gate phase)
    half8 xzr[2][4];
    #pragma unroll
    for (int mt = 0; mt < 2; ++mt)
      #pragma unroll
      for (int rr = 0; rr < 4; ++rr){
        int w = mt*16 + q*4 + rr;
        int p = (w == 0) ? t : 63 + w + t;
        xzr[mt][rr] = __builtin_nontemporal_load((const half8*)(xzb + (long)p*1024));
      }

    float4v acc[2][8];
    #pragma unroll
    for (int mt = 0; mt < 2; ++mt)
      #pragma unroll
      for (int n = 0; n < 8; ++n) acc[mt][n] = (float4v){0.f,0.f,0.f,0.f};

    // K-loop: A from group h-buffer (global, L2-hot), B from LDS-resident rk
    short8 a0 = Rb[((2*wv + 0)*8 + 0)*64 + lane];
    short8 a1 = Rb[((2*wv + 1)*8 + 0)*64 + lane];
    #pragma unroll
    for (int ks = 0; ks < 8; ++ks){
      short8 a0c = a0, a1c = a1;
      if (ks < 7){
        a0 = Rb[((2*wv + 0)*8 + ks + 1)*64 + lane];
        a1 = Rb[((2*wv + 1)*8 + ks + 1)*64 + lane];
      }
      #pragma unroll
      for (int f = 0; f < 8; ++f){
        short8 b = WK[(ks*8 + f)*64 + lane];
        acc[0][f] = __builtin_amdgcn_mfma_f32_16x16x32_bf16(a0c, b, acc[0][f], 0, 0, 0);
        acc[1][f] = __builtin_amdgcn_mfma_f32_16x16x32_bf16(a1c, b, acc[1][f], 0, 0, 0);
      }
    }

    // gates: C/D row = q*4+rr (chain-in-tile), col = lc -> j = r*32+tj*16+lc
    #pragma unroll
    for (int mt = 0; mt < 2; ++mt){
      #pragma unroll
      for (int rr = 0; rr < 4; ++rr){
        int w = mt*16 + q*4 + rr;
        int p = (w == 0) ? t : 63 + w + t;
        unsigned long long mm = (p < 64) ? m0 : ((p < 128) ? m1 : m2);
        bool msk = (mm >> (p & 63)) & 1ull;
        #pragma unroll
        for (int tj = 0; tj < 2; ++tj){
          float zi = acc[mt][0+tj][rr] + (float)xzr[mt][rr][0+tj];
          float zf = acc[mt][2+tj][rr] + (float)xzr[mt][rr][2+tj];
          float zc = acc[mt][4+tj][rr] + (float)xzr[mt][rr][4+tj];
          float zo = acc[mt][6+tj][rr] + (float)xzr[mt][rr][6+tj];
          float c0 = creg[mt][rr][tj];
          float ig = fsig(zi + c0*wcir[tj]);
          float fg = fsig(zf + c0*wcfr[tj]);
          float cn = fg*c0 + ig*ftanh(zc);
          float og = fsig(zo + cn*wcor[tj]);
          float hn = og*ftanh(cn);
          float hv = msk ? hn : hreg[mt][rr][tj];
          float cv = msk ? cn : c0;
          hreg[mt][rr][tj] = hv;
          creg[mt][rr][tj] = cv;
          // scatter h into A-fragment order of the group h-buffer:
          // tile (2wv+mt, ks=r), lane' = (q*4+rr) + 16*(tj*2+(lc>>3)), elem lc&7
          int lp = (q*4 + rr) + 16*(tj*2 + (lc >> 3));
          Wb[(((2*wv + mt)*8 + r)*64 + lp)*8 + (lc & 7)] = f2bf(hv);
        }
      }
    }

    GBAR(8*(s + 2));
  }

  // ---- final h (fp32) overwrites the group's h-buffer: [c 256][j 256] ----
  float* HF = (float*)HBg;
  #pragma unroll
  for (int mt = 0; mt < 2; ++mt)
    #pragma unroll
    for (int rr = 0; rr < 4; ++rr){
      int c = wv*32 + mt*16 + q*4 + rr;
      #pragma unroll
      for (int tj = 0; tj < 2; ++tj){
        int j = r*32 + tj*16 + lc;
        HF[c*256 + j] = hreg[mt][rr][tj];
      }
    }
  #undef GBAR
}

// ---------------------------------------------------------------------------
// h_avg = 0.5(h_f + h_b); cos = |q.d|/(|q||d|); softmax over 31 docs.
// Reads fp32 final-h from the group h-buffers.
// ---------------------------------------------------------------------------
__global__ void finalize(const char* __restrict__ hb, float* __restrict__ out){
  __shared__ float hav[32*256];
  __shared__ float dotl[32], sql[32];
  const int bat = blockIdx.x;
  const int tid = threadIdx.x;
  const float* hf = (const float*)(hb + (size_t)(bat >> 3)*262144)        + (bat & 7)*32*256;
  const float* hbp= (const float*)(hb + (size_t)(16 + (bat >> 3))*262144) + (bat & 7)*32*256;
  for (int i = tid; i < 8192; i += 256) hav[i] = 0.5f*(hf[i] + hbp[i]);
  __syncthreads();
  const int lane = tid & 63, wv = tid >> 6;
  for (int n = wv; n < 32; n += 4){
    float s1 = 0.f, s2 = 0.f;
    for (int j = lane; j < 256; j += 64){
      float a  = hav[n*256 + j];
      float qv = hav[j];
      s1 += a*qv; s2 += a*a;
    }
    #pragma unroll
    for (int off = 32; off; off >>= 1){
      s1 += __shfl_down(s1, off);
      s2 += __shfl_down(s2, off);
    }
    if (lane == 0){ dotl[n] = s1; sql[n] = s2; }
  }
  __syncthreads();
  if (wv == 0){
    float cosv = -1e30f;
    if (lane < 31)
      cosv = fabsf(dotl[lane+1]) / (sqrtf(sql[0]) * sqrtf(sql[lane+1]));
    float mx = cosv;
    #pragma unroll
    for (int off = 32; off; off >>= 1) mx = fmaxf(mx, __shfl_xor(mx, off));
    float e = (lane < 31) ? __expf(cosv - mx) : 0.f;
    float sum = e;
    #pragma unroll
    for (int off = 32; off; off >>= 1) sum += __shfl_xor(sum, off);
    if (lane < 31) out[bat*31 + lane] = e / sum;
  }
}

extern "C" void kernel_launch(void* const* d_in, const int* in_sizes, int n_in,
                              void* d_out, int out_size, void* d_ws, size_t ws_size,
                              hipStream_t stream) {
  const int*   inputs = (const int*)  d_in[0];
  const float* emb    = (const float*)d_in[1];
  const float* k_f    = (const float*)d_in[2];
  const float* rk_f   = (const float*)d_in[3];
  const float* b_f    = (const float*)d_in[4];
  const float* wci_f  = (const float*)d_in[5];
  const float* wcf_f  = (const float*)d_in[6];
  const float* wco_f  = (const float*)d_in[7];
  const float* k_b    = (const float*)d_in[8];
  const float* rk_b   = (const float*)d_in[9];
  const float* b_b    = (const float*)d_in[10];
  const float* wci_b  = (const float*)d_in[11];
  const float* wcf_b  = (const float*)d_in[12];
  const float* wco_b  = (const float*)d_in[13];

  char*           ws   = (char*)d_ws;
  unsigned short* rkp  = (unsigned short*)ws;
  unsigned short* kp   = (unsigned short*)(ws + OFF_KP);
  _Float16*       xzp  = (_Float16*)     (ws + OFF_XZ);

  prepack<<<(RKP_SHORTS + KP_SHORTS)/256, 256, 0, stream>>>(k_f, rk_f, k_b, rk_b, rkp, kp);
  xzgemm <<<128*2*5, 512, 0, stream>>>(inputs, emb, kp, b_f, b_b, xzp);
  hipMemsetAsync(ws + OFF_CTR, 0, 128, stream);   // group-barrier counters
  lstm_rec<<<256, 512, 0, stream>>>(inputs, xzp, rkp,
                                    wci_f, wcf_f, wco_f,
                                    wci_b, wcf_b, wco_b, ws);
  finalize<<<128, 256, 0, stream>>>(ws + OFF_HB, (float*)d_out);
}

// Round 6
// 1906.531 us; speedup vs baseline: 5.0806x; 5.0806x over previous
//
#include <hip/hip_runtime.h>

// Problem constants
#define NPOS   158   // 64 query + 94 doc token positions per batch
#define EPITCH 136   // shorts per staged emb row (128 + 8 pad)

// workspace layout (bytes)
#define WQ_SHORTS (2*8*8*8*64*8)           // 524288: [dir][wv8][ks8][f8][lane64][j8]
#define KP_SHORTS (2*64*4*512)             // k packed for xzgemm
#define XZ_HALFS  ((size_t)2*128*158*1024)
#define OFF_KP    ((size_t)WQ_SHORTS*2)                 // 1,048,576
#define OFF_XZ    (OFF_KP + (size_t)KP_SHORTS*2)        // 1,572,864
#define OFF_HOUT  (OFF_XZ + XZ_HALFS*2)                 // 84,410,368

typedef __attribute__((ext_vector_type(8))) short    short8;
typedef __attribute__((ext_vector_type(4))) short    short4v;
typedef __attribute__((ext_vector_type(4))) float    float4v;
typedef __attribute__((ext_vector_type(8))) _Float16 half8;

__device__ __forceinline__ unsigned short f2bf(float x){
  unsigned int u = __builtin_bit_cast(unsigned int, x);
  u += 0x7FFFu + ((u >> 16) & 1u);           // round-to-nearest-even
  return (unsigned short)(u >> 16);
}
__device__ __forceinline__ float fsig(float x){
  return 1.0f/(1.0f + __expf(-x));
}
__device__ __forceinline__ float ftanh(float x){
  float ax = fabsf(x);
  float e  = __expf(-2.0f*ax);
  float r  = (1.0f - e)/(1.0f + e);
  return (x < 0.0f) ? -r : r;
}

// async global->LDS DMA: 16B/lane, lds dst = wave-uniform base + lane*16
__device__ __forceinline__ void dma16(const void* g, void* l){
  __builtin_amdgcn_global_load_lds((const __attribute__((address_space(1))) void*)g,
                                   (__attribute__((address_space(3))) void*)l, 16, 0, 0);
}

// ---------------------------------------------------------------------------
// Pack rk into per-(dir,wave) DMA slice order:
//   wq[dir][wv 8][ks 8][f 8][lane 64][j 8], f = gate*2+tj, nt = gate*16+wv*2+tj,
//   element = rk[k = ks*32+(lane>>4)*8+j][col = nt*16+(lane&15)].
// Each (wv,ks) slice is 8 KB contiguous = 8 DMAs of 1 KB (one per f).
// Also pack k (for xzgemm): kp[dir][nt64][ks4][lane64][j8].
// ---------------------------------------------------------------------------
__global__ void prepack(const float* __restrict__ kf, const float* __restrict__ rkf,
                        const float* __restrict__ kb, const float* __restrict__ rkb,
                        unsigned short* __restrict__ wq, unsigned short* __restrict__ kp){
  int idx = blockIdx.x*256 + threadIdx.x;
  if (idx < WQ_SHORTS){
    int j = idx & 7, lane = (idx>>3)&63, f = (idx>>9)&7, ks = (idx>>12)&7,
        wv = (idx>>15)&7, d = (idx>>18)&1;
    int gate = f>>1, tj = f&1;
    int nt  = gate*16 + wv*2 + tj;
    int k   = ks*32 + (lane>>4)*8 + j;
    int col = nt*16 + (lane&15);
    const float* RK = d ? rkb : rkf;
    wq[idx] = f2bf(RK[k*1024 + col]);
  } else {
    int i2 = idx - WQ_SHORTS;
    if (i2 < KP_SHORTS){
      int j = i2 & 7, lane = (i2>>3)&63, ks = (i2>>9)&3, nt = (i2>>11)&63, d = i2>>17;
      const float* K = d ? kb : kf;
      int k   = ks*32 + (lane>>4)*8 + j;
      int col = nt*16 + (lane&15);
      kp[i2] = f2bf(K[k*1024 + col]);
    }
  }
}

// ---------------------------------------------------------------------------
// xz[dir][bat][pos][1024] (fp16) = emb @ k + bias, inner layout
// [pos][wv 8][lc 16][n 8], n = gate*2+tj.
// ---------------------------------------------------------------------------
__launch_bounds__(512)
__global__ void xzgemm(const int* __restrict__ inputs, const float* __restrict__ emb,
                       const unsigned short* __restrict__ kpack,
                       const float* __restrict__ b_f, const float* __restrict__ b_b,
                       _Float16* __restrict__ xz){
  __shared__ int tokp[32];
  __shared__ __align__(16) short e_lds[32*EPITCH];
  const int bid = blockIdx.x;
  const int pt  = bid % 5;
  const int bd  = bid / 5;
  const int bat = bd & 127, dir = bd >> 7;
  const int tid = threadIdx.x, lane = tid & 63, wv = tid >> 6;
  const int lc  = lane & 15, q = lane >> 4;

  for (int i = tid; i < 32*EPITCH; i += 512) e_lds[i] = 0;
  if (tid < 32){
    int p = pt*32 + tid;
    tokp[tid] = (p < NPOS) ? inputs[bat*NPOS + p] : 0;
  }
  __syncthreads();
  for (int idx = tid; idx < 32*32; idx += 512){
    int i = idx >> 5, c4 = (idx & 31) << 2;
    int p = pt*32 + i;
    if (p < NPOS){
      float4v v = *(const float4v*)(emb + (long)tokp[i]*128 + c4);
      short4v s;
      s[0]=(short)f2bf(v[0]); s[1]=(short)f2bf(v[1]);
      s[2]=(short)f2bf(v[2]); s[3]=(short)f2bf(v[3]);
      *(short4v*)&e_lds[i*EPITCH + c4] = s;
    }
  }
  __syncthreads();

  const float* bias = dir ? b_b : b_f;
  float4v acc[2][8];
  #pragma unroll
  for (int g = 0; g < 4; ++g)
    #pragma unroll
    for (int tj = 0; tj < 2; ++tj){
      float bv = bias[g*256 + wv*32 + tj*16 + lc];
      acc[0][g*2+tj] = (float4v){bv,bv,bv,bv};
      acc[1][g*2+tj] = acc[0][g*2+tj];
    }

  const short8* KP = (const short8*)kpack + (long)dir*64*4*64;
  #pragma unroll
  for (int ks = 0; ks < 4; ++ks){
    short8 a0 = *(const short8*)&e_lds[lc*EPITCH + ks*32 + q*8];
    short8 a1 = *(const short8*)&e_lds[(16+lc)*EPITCH + ks*32 + q*8];
    #pragma unroll
    for (int n = 0; n < 8; ++n){
      int g = n >> 1, tj = n & 1;
      int nt = g*16 + wv*2 + tj;
      short8 b = KP[(nt*4 + ks)*64 + lane];
      acc[0][n] = __builtin_amdgcn_mfma_f32_16x16x32_bf16(a0, b, acc[0][n], 0, 0, 0);
      acc[1][n] = __builtin_amdgcn_mfma_f32_16x16x32_bf16(a1, b, acc[1][n], 0, 0, 0);
    }
  }

  _Float16* xzb = xz + ((long)(dir*128 + bat))*NPOS*1024;
  #pragma unroll
  for (int mt = 0; mt < 2; ++mt)
    #pragma unroll
    for (int r = 0; r < 4; ++r){
      int row = mt*16 + q*4 + r;
      int p = pt*32 + row;
      if (p < NPOS){
        half8 hv;
        #pragma unroll
        for (int n = 0; n < 8; ++n) hv[n] = (_Float16)acc[mt][n][r];
        __builtin_nontemporal_store(hv, (half8*)(xzb + (long)p*1024 + wv*128 + lc*8));
      }
    }
}

// ---------------------------------------------------------------------------
// Recurrent kernel: block = (batch,dir), 32 chains, 64 steps, K=256.
// Weights stream via per-wave global_load_lds ring: 2 bufs x 8 KB (one
// K-slice each), 8 DMAs of 1 KB per slice, refill slice k+2 after consuming
// slice k. Static wait schedule: vmcnt(8) for slices 0..5, vmcnt(16) for
// 6..7 and the gate phase (accounts the 8 xz loads issued at slice 5).
// Step barriers are LGKM-ONLY (s_waitcnt lgkmcnt(0); s_barrier) so in-flight
// DMAs survive across steps. LDS: 16 KB h (single, XOR-swizzled) + 128 KB
// ring = 144 KB dynamic -> 1 block/CU.
// ---------------------------------------------------------------------------
__launch_bounds__(512, 2)
__global__ void lstm_rec(const int* __restrict__ inputs, const _Float16* __restrict__ xz,
                         const unsigned short* __restrict__ wq,
                         const float* __restrict__ wci_f, const float* __restrict__ wcf_f,
                         const float* __restrict__ wco_f,
                         const float* __restrict__ wci_b, const float* __restrict__ wcf_b,
                         const float* __restrict__ wco_b,
                         float* __restrict__ h_out)
{
  extern __shared__ __align__(16) char smem[];
  short* h_lds = (short*)smem;          // 16384 B, swizzled: chunk u of row m at m*256+(u^m)*8
  char*  ring  = smem + 16384;          // 8 waves x 2 bufs x 8192 B

  const int tid  = threadIdx.x;
  const int lane = tid & 63;
  const int wv   = tid >> 6;
  const int lc   = lane & 15;
  const int q    = lane >> 4;
  const int bat  = blockIdx.x & 127;
  const int dir  = blockIdx.x >> 7;

  // h zero + masks (ballot; no LDS)
  for (int i = tid; i < 32*256; i += 512) h_lds[i] = 0;
  unsigned long long mk0 = __ballot(inputs[bat*NPOS + lane] != 0);
  unsigned long long mk1 = __ballot(inputs[bat*NPOS + 64 + lane] != 0);
  int p2 = 128 + lane;
  unsigned long long mk2 = __ballot((p2 < NPOS) && (inputs[bat*NPOS + p2] != 0));

  const float* wci = dir ? wci_b : wci_f;
  const float* wcf = dir ? wcf_b : wcf_f;
  const float* wco = dir ? wco_b : wco_f;
  float wcir[2], wcfr[2], wcor[2];
  #pragma unroll
  for (int tj = 0; tj < 2; ++tj){
    int j = wv*32 + tj*16 + lc;
    wcir[tj] = wci[j]; wcfr[tj] = wcf[j]; wcor[tj] = wco[j];
  }

  float hreg[2][4][2], creg[2][4][2];
  #pragma unroll
  for (int mt = 0; mt < 2; ++mt)
    #pragma unroll
    for (int rr = 0; rr < 4; ++rr)
      #pragma unroll
      for (int tj = 0; tj < 2; ++tj){ hreg[mt][rr][tj] = 0.f; creg[mt][rr][tj] = 0.f; }

  __syncthreads();   // h zeros visible; full barrier BEFORE any DMA is issued

  // per-(dir,wave) weight region: 8 slices x 8192 B; per-lane src has lane*16
  const char* wsrc = (const char*)wq + (size_t)(dir*8 + wv)*65536 + (size_t)lane*16;
  char*       wreg = ring + (size_t)wv*16384;
  const _Float16* xzb = xz + ((long)(dir*128 + bat))*NPOS*1024 + wv*128 + lc*8;

  // prologue: slices 0,1 -> bufs 0,1 (16 DMAs in flight)
  #pragma unroll
  for (int f = 0; f < 8; ++f) dma16(wsrc + 0*8192 + f*1024, wreg + 0*8192 + f*1024);
  #pragma unroll
  for (int f = 0; f < 8; ++f) dma16(wsrc + 1*8192 + f*1024, wreg + 1*8192 + f*1024);

  const int m0 = lc, m1 = 16 + lc;

  for (int s = 0; s < 64; ++s){
    const int t = dir ? (63 - s) : s;

    float4v acc[2][8];
    #pragma unroll
    for (int mt = 0; mt < 2; ++mt)
      #pragma unroll
      for (int n = 0; n < 8; ++n) acc[mt][n] = (float4v){0.f,0.f,0.f,0.f};

    half8 xzr[2][4];

    #pragma unroll
    for (int ks = 0; ks < 8; ++ks){
      // consume gate: slice ks was DMA'd 2 slices ago; younger ops =
      // 8 (one refill batch) for ks<=5, +8 xz for ks in {6,7}.
      if (ks < 6) asm volatile("s_waitcnt vmcnt(8)"  ::: "memory");
      else        asm volatile("s_waitcnt vmcnt(16)" ::: "memory");

      const char* bp = wreg + (ks & 1)*8192;
      short8 a0 = *(const short8*)&h_lds[m0*256 + ((4*ks + q) ^ m0)*8];
      short8 a1 = *(const short8*)&h_lds[m1*256 + ((4*ks + q) ^ m1)*8];
      #pragma unroll
      for (int f = 0; f < 8; ++f){
        short8 b = *(const short8*)(bp + f*1024 + (size_t)lane*16);
        acc[0][f] = __builtin_amdgcn_mfma_f32_16x16x32_bf16(a0, b, acc[0][f], 0, 0, 0);
        acc[1][f] = __builtin_amdgcn_mfma_f32_16x16x32_bf16(a1, b, acc[1][f], 0, 0, 0);
      }
      // refill: slice (ks+2)&7 into the buffer just consumed (same parity).
      // Weights identical every step, so wrap-around just re-loads slices 0,1.
      {
        const char* gs = wsrc + ((ks + 2) & 7)*8192;
        char*       ds = wreg + (ks & 1)*8192;
        #pragma unroll
        for (int f = 0; f < 8; ++f) dma16(gs + f*1024, ds + f*1024);
      }
      if (ks == 5){
        // this step's xz: issued after refill5, consumed in gate phase
        #pragma unroll
        for (int mt = 0; mt < 2; ++mt)
          #pragma unroll
          for (int rr = 0; rr < 4; ++rr){
            int m = mt*16 + q*4 + rr;
            int p = (m == 0) ? t : 63 + m + t;
            xzr[mt][rr] = __builtin_nontemporal_load((const half8*)(xzb + (long)p*1024));
          }
      }
    }

    // barrier 1: all waves done READING h_lds (LGKM only; DMAs stay in flight)
    asm volatile("s_waitcnt lgkmcnt(0)\n\ts_barrier" ::: "memory");
    // xz ready once the two post-xz refill batches are the only younger ops
    asm volatile("s_waitcnt vmcnt(16)" ::: "memory");

    // gates: C/D row = q*4+rr (chain), col = lc
    #pragma unroll
    for (int mt = 0; mt < 2; ++mt){
      #pragma unroll
      for (int rr = 0; rr < 4; ++rr){
        int m = mt*16 + q*4 + rr;
        int p = (m == 0) ? t : 63 + m + t;
        unsigned long long mm = (p < 64) ? mk0 : ((p < 128) ? mk1 : mk2);
        bool msk = (mm >> (p & 63)) & 1ull;
        #pragma unroll
        for (int tj = 0; tj < 2; ++tj){
          float zi = acc[mt][0+tj][rr] + (float)xzr[mt][rr][0+tj];
          float zf = acc[mt][2+tj][rr] + (float)xzr[mt][rr][2+tj];
          float zc = acc[mt][4+tj][rr] + (float)xzr[mt][rr][4+tj];
          float zo = acc[mt][6+tj][rr] + (float)xzr[mt][rr][6+tj];
          float c0 = creg[mt][rr][tj];
          float ig = fsig(zi + c0*wcir[tj]);
          float fg = fsig(zf + c0*wcfr[tj]);
          float cn = fg*c0 + ig*ftanh(zc);
          float og = fsig(zo + cn*wcor[tj]);
          float hn = og*ftanh(cn);
          float hv = msk ? hn : hreg[mt][rr][tj];
          float cv = msk ? cn : c0;
          hreg[mt][rr][tj] = hv;
          creg[mt][rr][tj] = cv;
          int u = wv*4 + tj*2 + (lc >> 3);
          h_lds[m*256 + (u ^ m)*8 + (lc & 7)] = (short)f2bf(hv);
        }
      }
    }
    // barrier 2: h writes visible before next step's reads (LGKM only)
    asm volatile("s_waitcnt lgkmcnt(0)\n\ts_barrier" ::: "memory");
  }

  #pragma unroll
  for (int mt = 0; mt < 2; ++mt)
    #pragma unroll
    for (int rr = 0; rr < 4; ++rr){
      int m = mt*16 + q*4 + rr;
      #pragma unroll
      for (int tj = 0; tj < 2; ++tj){
        int j = wv*32 + tj*16 + lc;
        h_out[(((long)dir*128 + bat)*32 + m)*256 + j] = hreg[mt][rr][tj];
      }
    }
}

// ---------------------------------------------------------------------------
// h_avg = 0.5(h_f + h_b); cos = |q.d|/(|q||d|); softmax over 31 docs.
// ---------------------------------------------------------------------------
__global__ void finalize(const float* __restrict__ h_out, float* __restrict__ out){
  __shared__ float hav[32*256];
  __shared__ float dotl[32], sql[32];
  const int bat = blockIdx.x;
  const int tid = threadIdx.x;
  const float* hf = h_out + (long)bat*8192;
  const float* hb = h_out + (long)(128 + bat)*8192;
  for (int i = tid; i < 8192; i += 256) hav[i] = 0.5f*(hf[i] + hb[i]);
  __syncthreads();
  const int lane = tid & 63, wv = tid >> 6;
  for (int n = wv; n < 32; n += 4){
    float s1 = 0.f, s2 = 0.f;
    for (int j = lane; j < 256; j += 64){
      float a  = hav[n*256 + j];
      float qv = hav[j];
      s1 += a*qv; s2 += a*a;
    }
    #pragma unroll
    for (int off = 32; off; off >>= 1){
      s1 += __shfl_down(s1, off);
      s2 += __shfl_down(s2, off);
    }
    if (lane == 0){ dotl[n] = s1; sql[n] = s2; }
  }
  __syncthreads();
  if (wv == 0){
    float cosv = -1e30f;
    if (lane < 31)
      cosv = fabsf(dotl[lane+1]) / (sqrtf(sql[0]) * sqrtf(sql[lane+1]));
    float mx = cosv;
    #pragma unroll
    for (int off = 32; off; off >>= 1) mx = fmaxf(mx, __shfl_xor(mx, off));
    float e = (lane < 31) ? __expf(cosv - mx) : 0.f;
    float sum = e;
    #pragma unroll
    for (int off = 32; off; off >>= 1) sum += __shfl_xor(sum, off);
    if (lane < 31) out[bat*31 + lane] = e / sum;
  }
}

extern "C" void kernel_launch(void* const* d_in, const int* in_sizes, int n_in,
                              void* d_out, int out_size, void* d_ws, size_t ws_size,
                              hipStream_t stream) {
  const int*   inputs = (const int*)  d_in[0];
  const float* emb    = (const float*)d_in[1];
  const float* k_f    = (const float*)d_in[2];
  const float* rk_f   = (const float*)d_in[3];
  const float* b_f    = (const float*)d_in[4];
  const float* wci_f  = (const float*)d_in[5];
  const float* wcf_f  = (const float*)d_in[6];
  const float* wco_f  = (const float*)d_in[7];
  const float* k_b    = (const float*)d_in[8];
  const float* rk_b   = (const float*)d_in[9];
  const float* b_b    = (const float*)d_in[10];
  const float* wci_b  = (const float*)d_in[11];
  const float* wcf_b  = (const float*)d_in[12];
  const float* wco_b  = (const float*)d_in[13];

  unsigned short* wqp  = (unsigned short*)d_ws;
  unsigned short* kp   = (unsigned short*)((char*)d_ws + OFF_KP);
  _Float16*       xzp  = (_Float16*)     ((char*)d_ws + OFF_XZ);
  float*          hout = (float*)        ((char*)d_ws + OFF_HOUT);

  prepack<<<(WQ_SHORTS + KP_SHORTS)/256, 256, 0, stream>>>(k_f, rk_f, k_b, rk_b, wqp, kp);
  xzgemm <<<128*2*5, 512, 0, stream>>>(inputs, emb, kp, b_f, b_b, xzp);
  lstm_rec<<<256, 512, 147456, stream>>>(inputs, xzp, wqp,
                                         wci_f, wcf_f, wco_f,
                                         wci_b, wcf_b, wco_b, hout);
  finalize<<<128, 256, 0, stream>>>(hout, (float*)d_out);
}